// Round 2
// baseline (1571.492 us; speedup 1.0000x reference)
//
#include <hip/hip_runtime.h>

#define BB 64
#define TT 2048
#define INW 64
#define HH 256

typedef float v2f __attribute__((ext_vector_type(2)));

__device__ __forceinline__ v2f fma2(v2f a, v2f b, v2f c) {
#if __has_builtin(__builtin_elementwise_fma)
    return __builtin_elementwise_fma(a, b, c);   // -> v_pk_fma_f32
#else
    v2f r; r.x = __builtin_fmaf(a.x, b.x, c.x); r.y = __builtin_fmaf(a.y, b.y, c.y); return r;
#endif
}

__device__ __forceinline__ float fast_tanh(float x) {
    // tanh(x) = 1 - 2/(e^{2x}+1); saturates correctly at +/-inf
    float e = __expf(2.0f * x);
    return 1.0f - 2.0f / (e + 1.0f);
}

// One workgroup per batch, 512 threads.
// Thread decomposition: h2 = tid & 127, q = tid >> 7  (q in [0,4)).
// Thread (h2,q) owns W_rec rows {h2, h2+128}, k-range [64q, 64q+64), and
// W_in rows {h2, h2+128}, j-range [16q, 16q+16) -- all in registers (160 f32).
// Per step: partial dots -> part[q][h] -> barrier -> 256 threads combine,
// update u, write u_out, write r_buf -> barrier.
__global__ __launch_bounds__(512, 2)
void rnn_scan(const float* __restrict__ x0,
              const float* __restrict__ I,
              const float* __restrict__ W_in,
              const float* __restrict__ W_rec,
              const float* __restrict__ bias,
              float* __restrict__ u_out)
{
    __shared__ __align__(16) float r_buf[HH];
    __shared__ __align__(16) float i_buf[INW];
    __shared__ float part[4][HH + 1];

    const int b   = blockIdx.x;
    const int tid = threadIdx.x;
    const int h2  = tid & 127;
    const int q   = tid >> 7;          // wave-uniform (waves 2w, 2w+1 share q)
    const int k0  = q * 64;
    const int j0  = q * 16;
    const int hA  = h2;
    const int hB  = h2 + 128;

    // ---- loop-invariant weights into registers ----
    v2f wrA[32], wrB[32], wiA[8], wiB[8];
    {
        const float4* wa = (const float4*)(W_rec + (size_t)hA * HH + k0);
        const float4* wb = (const float4*)(W_rec + (size_t)hB * HH + k0);
        #pragma unroll
        for (int i = 0; i < 16; ++i) {
            float4 a = wa[i], bq = wb[i];
            wrA[2*i]     = (v2f){a.x, a.y};  wrA[2*i + 1] = (v2f){a.z, a.w};
            wrB[2*i]     = (v2f){bq.x, bq.y}; wrB[2*i + 1] = (v2f){bq.z, bq.w};
        }
        const float4* ia = (const float4*)(W_in + (size_t)hA * INW + j0);
        const float4* ib = (const float4*)(W_in + (size_t)hB * INW + j0);
        #pragma unroll
        for (int i = 0; i < 4; ++i) {
            float4 a = ia[i], bq = ib[i];
            wiA[2*i]     = (v2f){a.x, a.y};  wiA[2*i + 1] = (v2f){a.z, a.w};
            wiB[2*i]     = (v2f){bq.x, bq.y}; wiB[2*i + 1] = (v2f){bq.z, bq.w};
        }
    }

    // ---- state init ----
    float u = 0.0f, bv = 0.0f;
    if (tid < HH) {
        u  = x0[(size_t)b * HH + tid];
        bv = bias[tid];
        r_buf[tid] = fast_tanh(u);
    }
    if (tid < INW) i_buf[tid] = I[((size_t)b * TT + 0) * INW + tid];
    __syncthreads();

    const float4* rb4 = (const float4*)&r_buf[k0];
    const float4* ib4 = (const float4*)&i_buf[j0];

    for (int t = 0; t < TT; ++t) {
        // prefetch next input row (independent, hides HBM latency)
        float i_next = 0.0f;
        if (tid < INW && (t + 1) < TT)
            i_next = I[((size_t)b * TT + (t + 1)) * INW + tid];

        v2f aA0 = {0.f,0.f}, aA1 = {0.f,0.f}, aB0 = {0.f,0.f}, aB1 = {0.f,0.f};
        #pragma unroll
        for (int i = 0; i < 16; ++i) {
            float4 r4 = rb4[i];                       // wave-uniform -> LDS broadcast
            v2f r01 = (v2f){r4.x, r4.y}, r23 = (v2f){r4.z, r4.w};
            aA0 = fma2(wrA[2*i],     r01, aA0);
            aA1 = fma2(wrA[2*i + 1], r23, aA1);
            aB0 = fma2(wrB[2*i],     r01, aB0);
            aB1 = fma2(wrB[2*i + 1], r23, aB1);
        }
        #pragma unroll
        for (int i = 0; i < 4; ++i) {
            float4 r4 = ib4[i];
            v2f r01 = (v2f){r4.x, r4.y}, r23 = (v2f){r4.z, r4.w};
            aA0 = fma2(wiA[2*i],     r01, aA0);
            aA1 = fma2(wiA[2*i + 1], r23, aA1);
            aB0 = fma2(wiB[2*i],     r01, aB0);
            aB1 = fma2(wiB[2*i + 1], r23, aB1);
        }
        v2f sA = aA0 + aA1, sB = aB0 + aB1;
        part[q][hA] = sA.x + sA.y;
        part[q][hB] = sB.x + sB.y;
        __syncthreads();                               // partials visible; r/i reads done

        if (tid < HH) {
            float d = ((part[0][tid] + part[1][tid]) + (part[2][tid] + part[3][tid])) + bv;
            u = 0.8f * u + 0.2f * d;
            u_out[((size_t)b * TT + t) * HH + tid] = u;
            r_buf[tid] = fast_tanh(u);
        }
        if (tid < INW) i_buf[tid] = i_next;
        __syncthreads();                               // new r/i visible for t+1
    }
}

// y[b,t,o] = sum_h u[b,t,h] * Wout[o,h] + bout[o]. One wave per (b,t) row.
__global__ __launch_bounds__(256)
void readout(const float* __restrict__ u,
             const float* __restrict__ Wout,
             const float* __restrict__ bout,
             float* __restrict__ y)
{
    const int wid  = threadIdx.x >> 6;
    const int lane = threadIdx.x & 63;
    const size_t row = (size_t)blockIdx.x * 4 + wid;   // < BB*TT

    float4 uv = ((const float4*)(u + row * HH))[lane];
    float4 w0 = ((const float4*)Wout)[lane];
    float4 w1 = ((const float4*)(Wout + HH))[lane];

    float acc0 = uv.x * w0.x + uv.y * w0.y + uv.z * w0.z + uv.w * w0.w;
    float acc1 = uv.x * w1.x + uv.y * w1.y + uv.z * w1.z + uv.w * w1.w;

    #pragma unroll
    for (int m = 32; m >= 1; m >>= 1) {
        acc0 += __shfl_xor(acc0, m, 64);
        acc1 += __shfl_xor(acc1, m, 64);
    }
    if (lane == 0) {
        y[row * 2 + 0] = acc0 + bout[0];
        y[row * 2 + 1] = acc1 + bout[1];
    }
}

extern "C" void kernel_launch(void* const* d_in, const int* in_sizes, int n_in,
                              void* d_out, int out_size, void* d_ws, size_t ws_size,
                              hipStream_t stream) {
    const float* x0    = (const float*)d_in[0];
    const float* I     = (const float*)d_in[1];
    const float* W_in  = (const float*)d_in[2];
    const float* W_rec = (const float*)d_in[3];
    const float* bias  = (const float*)d_in[4];
    const float* Wout  = (const float*)d_in[5];
    const float* bout  = (const float*)d_in[6];

    float* u_out = (float*)d_out;
    float* y_out = u_out + (size_t)BB * TT * HH;

    rnn_scan<<<BB, 512, 0, stream>>>(x0, I, W_in, W_rec, bias, u_out);
    readout<<<(BB * TT) / 4, 256, 0, stream>>>(u_out, Wout, bout, y_out);
}